// Round 4
// baseline (320.607 us; speedup 1.0000x reference)
//
#include <hip/hip_runtime.h>
#include <hip/hip_bf16.h>

// Problem constants: features [B=32, D=1024, M=512] fp32.
#define B_ 32
#define D_ 1024
#define M_ 512
#define OUTROW 524800  // D*(D+1)/2
#define ALPHA_ 0.4f
#define EPS_ 1e-5f

typedef __bf16 bf16x8 __attribute__((ext_vector_type(8)));
typedef float f32x4 __attribute__((ext_vector_type(4)));

// ---------------------------------------------------------------------------
// Kernel A: cast features fp32->bf16 + diag[b,d] = sum_m f^2 / (2M) (fp32).
// One wave per row (512 elems), 4 rows per 256-thread block.
// ---------------------------------------------------------------------------
__global__ __launch_bounds__(256) void prep_kernel(
    const float* __restrict__ feat, __bf16* __restrict__ featbf,
    float* __restrict__ diag)
{
    const int w = threadIdx.x >> 6, l = threadIdx.x & 63;
    const int row = blockIdx.x * 4 + w;          // 0 .. 32767
    const float4* fp = (const float4*)(feat + (size_t)row * M_);
    float4 v0 = fp[l * 2];
    float4 v1 = fp[l * 2 + 1];
    bf16x8 h;
    h[0] = (__bf16)v0.x; h[1] = (__bf16)v0.y; h[2] = (__bf16)v0.z; h[3] = (__bf16)v0.w;
    h[4] = (__bf16)v1.x; h[5] = (__bf16)v1.y; h[6] = (__bf16)v1.z; h[7] = (__bf16)v1.w;
    *(bf16x8*)(featbf + (size_t)row * M_ + l * 8) = h;
    float s = v0.x*v0.x + v0.y*v0.y + v0.z*v0.z + v0.w*v0.w
            + v1.x*v1.x + v1.y*v1.y + v1.z*v1.z + v1.w*v1.w;
    #pragma unroll
    for (int off = 32; off; off >>= 1) s += __shfl_down(s, off);
    if (l == 0) diag[row] = s * (1.0f / (2.0f * M_));
}

// ---------------------------------------------------------------------------
// Kernel B: upper-triangular-tile Gram GEMM (bf16 MFMA 16x16x32), fused
// dcov -> pow epilogue. 64x64 tiles -> 136 pairs x 32 batches = 4352 blocks
// (17/CU) for occupancy-based latency hiding. BK=64 single-buffer, 16 KB LDS,
// conflict-free layout (8 chunks/row = 128B stride, XOR-(row&7) swizzle —
// the R2 layout measured at 0 conflicts; R3's BK=32 64B-stride variant had
// 2.36M conflict cycles). XCD-batch swizzle keeps each XCD's 1MB/batch
// feature panels L2-resident (FETCH 118->19 MB measured).
// 4 waves in 2x2; each wave computes 32x32 via 2x2 16x16 frags.
// ---------------------------------------------------------------------------
__global__ __launch_bounds__(256, 6) void gram_kernel(
    const __bf16* __restrict__ feat, const float* __restrict__ diag,
    float* __restrict__ out, float* __restrict__ rowsum,
    float* __restrict__ totals)
{
    __shared__ __bf16 As[64 * 64];   // 8 KB : 64 rows x 8 chunks x 8 bf16
    __shared__ __bf16 Bs[64 * 64];   // 8 KB

    const int t = threadIdx.x;
    const int w = t >> 6, l = t & 63;
    const int quad = l >> 4, l15 = l & 15;

    // XCD-aware decode: block L -> XCD L%8 (dispatch round-robin); each XCD
    // owns batches {xcd, xcd+8, xcd+16, xcd+24} processed sequentially.
    const int L = blockIdx.x;
    const int xcd = L & 7;
    const int slot = L >> 3;                 // 0..543
    const int b = xcd + 8 * (slot / 136);
    int u = slot % 136, ti = 0;
    while (u >= 16 - ti) { u -= 16 - ti; ti++; }
    const int tj = ti + u;
    const bool diagTile = (ti == tj);

    const __bf16* Ab = feat + (size_t)b * (D_ * M_) + (size_t)ti * 64 * M_;
    const __bf16* Bb = feat + (size_t)b * (D_ * M_) + (size_t)tj * 64 * M_;

    const int wm = w >> 1, wn = w & 1;

    f32x4 acc[2][2] = {};

    for (int k0 = 0; k0 < M_; k0 += 64) {
        // stage A,B rows [0,64) cols [k0,k0+64): 512 16B-chunks each,
        // 2 glds per wave per matrix; LDS dest = wave-uniform base + lane*16.
        #pragma unroll
        for (int it = 0; it < 2; ++it) {
            const int idx = it * 256 + t;          // chunk slot 0..511
            const int row = idx >> 3;              // 0..63
            const int cg = (idx & 7) ^ (row & 7);  // swizzled chunk-of-8
            const __bf16* ga = Ab + row * M_ + k0 + cg * 8;
            const __bf16* gb = Bb + row * M_ + k0 + cg * 8;
            __builtin_amdgcn_global_load_lds(
                (const __attribute__((address_space(1))) void*)ga,
                (__attribute__((address_space(3))) void*)(As + (it * 256 + w * 64) * 8),
                16, 0, 0);
            __builtin_amdgcn_global_load_lds(
                (const __attribute__((address_space(1))) void*)gb,
                (__attribute__((address_space(3))) void*)(Bs + (it * 256 + w * 64) * 8),
                16, 0, 0);
        }
        __syncthreads();

        #pragma unroll
        for (int kk = 0; kk < 64; kk += 32) {
            bf16x8 af[2], bfr[2];
            #pragma unroll
            for (int mi = 0; mi < 2; ++mi) {
                const int row = wm * 32 + mi * 16 + l15;
                const int sc = ((kk >> 3) + quad) ^ (row & 7);
                af[mi] = *(const bf16x8*)(As + row * 64 + sc * 8);
            }
            #pragma unroll
            for (int nj = 0; nj < 2; ++nj) {
                const int row = wn * 32 + nj * 16 + l15;
                const int sc = ((kk >> 3) + quad) ^ (row & 7);
                bfr[nj] = *(const bf16x8*)(Bs + row * 64 + sc * 8);
            }
            #pragma unroll
            for (int mi = 0; mi < 2; ++mi)
                #pragma unroll
                for (int nj = 0; nj < 2; ++nj)
                    acc[mi][nj] = __builtin_amdgcn_mfma_f32_16x16x32_bf16(
                        af[mi], bfr[nj], acc[mi][nj], 0, 0, 0);
        }
        __syncthreads();
    }

    // ---------------- epilogue ----------------
    const int gi0 = ti * 64 + wm * 32;
    const int gj0 = tj * 64 + wn * 32;
    const float* diagB = diag + b * D_;

    float di[2][4], dj[2];
    #pragma unroll
    for (int mi = 0; mi < 2; ++mi)
        #pragma unroll
        for (int r = 0; r < 4; ++r)
            di[mi][r] = diagB[gi0 + mi * 16 + quad * 4 + r];
    #pragma unroll
    for (int nj = 0; nj < 2; ++nj)
        dj[nj] = diagB[gj0 + nj * 16 + l15];

    float* outB = out + (size_t)b * OUTROW;
    float rs[2][4] = {};
    float cs[2] = {};
    float wt = 0.f;
    const float invK = 1.0f / 512.0f;  // dcov = di + dj - dot/512

    #pragma unroll
    for (int mi = 0; mi < 2; ++mi) {
        #pragma unroll
        for (int nj = 0; nj < 2; ++nj) {
            const f32x4 a = acc[mi][nj];
            const int j = gj0 + nj * 16 + l15;
            #pragma unroll
            for (int r = 0; r < 4; ++r) {
                const int i = gi0 + mi * 16 + quad * 4 + r;
                float d = di[mi][r] + dj[nj] - a[r] * invK;
                if (i == j) d = 0.0f;   // exact: ref has dcov(i,i) == 0
                d = fmaxf(d, 0.0f);
                const float p = __builtin_exp2f(ALPHA_ * __builtin_log2f(d + EPS_));
                rs[mi][r] += p;
                cs[nj] += p;
                wt += p;
                if (!diagTile || j >= i)
                    outB[(size_t)i * D_ - ((size_t)i * (i + 1)) / 2 + j] = p;
            }
        }
    }

    // row-sum contributions: reduce across l15 lanes
    #pragma unroll
    for (int mi = 0; mi < 2; ++mi) {
        #pragma unroll
        for (int r = 0; r < 4; ++r) {
            float v = rs[mi][r];
            v += __shfl_xor(v, 1); v += __shfl_xor(v, 2);
            v += __shfl_xor(v, 4); v += __shfl_xor(v, 8);
            if (l15 == 0)
                unsafeAtomicAdd(&rowsum[b * D_ + gi0 + mi * 16 + quad * 4 + r], v);
        }
    }
    // col-sum contributions map to rowsum[j] by symmetry (off-diag tiles only)
    if (!diagTile) {
        #pragma unroll
        for (int nj = 0; nj < 2; ++nj) {
            float v = cs[nj];
            v += __shfl_xor(v, 16); v += __shfl_xor(v, 32);
            if (quad == 0)
                unsafeAtomicAdd(&rowsum[b * D_ + gj0 + nj * 16 + l15], v);
        }
    }
    // batch total (off-diag tiles counted twice: tile + mirror)
    float v = wt;
    #pragma unroll
    for (int off = 32; off; off >>= 1) v += __shfl_down(v, off);
    if (l == 0) unsafeAtomicAdd(&totals[b], diagTile ? v : 2.0f * v);
}

// ---------------------------------------------------------------------------
// Kernel C: in-place double-centering. One block per (row i, batch b);
// threads stride the packed row. out[b,tri(i,j)] -= rm[i]+rm[j]-tm
// ---------------------------------------------------------------------------
__global__ __launch_bounds__(256) void center_kernel(
    float* __restrict__ out, const float* __restrict__ rowsum,
    const float* __restrict__ totals)
{
    const int i = blockIdx.x, b = blockIdx.y;
    const float* rsB = rowsum + b * D_;
    const float rmi = rsB[i] * (1.0f / D_);
    const float tm = totals[b] * (1.0f / ((float)D_ * (float)D_));
    float* row = out + (size_t)b * OUTROW + (size_t)i * D_ - ((size_t)i * (i + 1)) / 2;
    for (int j = i + threadIdx.x; j < D_; j += 256) {
        row[j] = row[j] - rmi - rsB[j] * (1.0f / D_) + tm;
    }
}

// ---------------------------------------------------------------------------
extern "C" void kernel_launch(void* const* d_in, const int* in_sizes, int n_in,
                              void* d_out, int out_size, void* d_ws, size_t ws_size,
                              hipStream_t stream) {
    const float* feat = (const float*)d_in[0];
    float* out = (float*)d_out;

    char* ws = (char*)d_ws;
    __bf16* featbf = (__bf16*)ws;                            // 33,554,432 B
    float* diag    = (float*)(ws + 33554432);                //    131,072 B
    float* rowsum  = (float*)(ws + 33554432 + 131072);       //    131,072 B
    float* totals  = (float*)(ws + 33554432 + 262144);       //        128 B

    // zero rowsum + totals (ws is re-poisoned 0xAA before every launch)
    (void)hipMemsetAsync(rowsum, 0, 131072 + 128, stream);

    prep_kernel<<<dim3((B_ * D_) / 4), dim3(256), 0, stream>>>(feat, featbf, diag);
    gram_kernel<<<dim3(136 * B_), dim3(256), 0, stream>>>(featbf, diag, out, rowsum, totals);
    center_kernel<<<dim3(D_, B_), dim3(256), 0, stream>>>(out, rowsum, totals);
}

// Round 5
// 218.047 us; speedup vs baseline: 1.4704x; 1.4704x over previous
//
#include <hip/hip_runtime.h>
#include <hip/hip_bf16.h>

// Problem constants: features [B=32, D=1024, M=512] fp32.
#define B_ 32
#define D_ 1024
#define M_ 512
#define OUTROW 524800  // D*(D+1)/2
#define ALPHA_ 0.4f
#define EPS_ 1e-5f

typedef __bf16 bf16x8 __attribute__((ext_vector_type(8)));
typedef float f32x4 __attribute__((ext_vector_type(4)));

// ---------------------------------------------------------------------------
// Kernel A: cast features fp32->bf16 + diag[b,d] = sum_m f^2 / (2M) (fp32).
// One wave per row (512 elems), 4 rows per 256-thread block.
// ---------------------------------------------------------------------------
__global__ __launch_bounds__(256) void prep_kernel(
    const float* __restrict__ feat, __bf16* __restrict__ featbf,
    float* __restrict__ diag)
{
    const int w = threadIdx.x >> 6, l = threadIdx.x & 63;
    const int row = blockIdx.x * 4 + w;          // 0 .. 32767
    const float4* fp = (const float4*)(feat + (size_t)row * M_);
    float4 v0 = fp[l * 2];
    float4 v1 = fp[l * 2 + 1];
    bf16x8 h;
    h[0] = (__bf16)v0.x; h[1] = (__bf16)v0.y; h[2] = (__bf16)v0.z; h[3] = (__bf16)v0.w;
    h[4] = (__bf16)v1.x; h[5] = (__bf16)v1.y; h[6] = (__bf16)v1.z; h[7] = (__bf16)v1.w;
    *(bf16x8*)(featbf + (size_t)row * M_ + l * 8) = h;
    float s = v0.x*v0.x + v0.y*v0.y + v0.z*v0.z + v0.w*v0.w
            + v1.x*v1.x + v1.y*v1.y + v1.z*v1.z + v1.w*v1.w;
    #pragma unroll
    for (int off = 32; off; off >>= 1) s += __shfl_down(s, off);
    if (l == 0) diag[row] = s * (1.0f / (2.0f * M_));
}

// ---------------------------------------------------------------------------
// Kernel B: upper-triangular-tile Gram GEMM (bf16 MFMA 16x16x32), fused
// dcov -> pow epilogue.
//   - 128x128 tile, BK=64, 4 waves (64x64 each, 4x4 frags)  [R2: proven]
//   - XOR-(row&7) chunk swizzle, 128B row stride: 0 bank conflicts [R2]
//   - XCD-batch swizzle: FETCH 118->19 MB, loads hit L2           [R3]
//   - double-buffered 2x32 KB LDS, prefetch issued AFTER the barrier so
//     the next stage's 32 glds are in flight during this k0's 32 MFMA;
//     the single barrier/k0 then drains a nearly-complete queue.
//   - launch_bounds(256,2): 256-VGPR budget (R4's (256,6)->32 VGPR choked).
// ---------------------------------------------------------------------------
__global__ __launch_bounds__(256, 2) void gram_kernel(
    const __bf16* __restrict__ feat, const float* __restrict__ diag,
    float* __restrict__ out, float* __restrict__ rowsum,
    float* __restrict__ totals)
{
    __shared__ __bf16 As[2][128 * 64];   // 2 x 16 KB
    __shared__ __bf16 Bs[2][128 * 64];   // 2 x 16 KB

    const int t = threadIdx.x;
    const int w = t >> 6, l = t & 63;
    const int quad = l >> 4, l15 = l & 15;

    // XCD-aware decode: block L -> XCD L%8; each XCD owns batches
    // {xcd, xcd+8, xcd+16, xcd+24} -> 1MB/batch panels stay L2-resident.
    const int L = blockIdx.x;
    const int xcd = L & 7;
    const int slot = L >> 3;                 // 0..143
    const int b = xcd + 8 * (slot / 36);
    int u = slot % 36, ti = 0;
    while (u >= 8 - ti) { u -= 8 - ti; ti++; }
    const int tj = ti + u;
    const bool diagTile = (ti == tj);

    const __bf16* Ab = feat + (size_t)b * (D_ * M_) + (size_t)ti * 128 * M_;
    const __bf16* Bb = feat + (size_t)b * (D_ * M_) + (size_t)tj * 128 * M_;

    const int wm = w >> 1, wn = w & 1;

    f32x4 acc[4][4] = {};

    // stage s (0..7): rows [0,128) cols [s*64, s*64+64) into buffer s&1
    auto stage = [&](int s) {
        const int koff = s * 64;
        const int sb = s & 1;
        #pragma unroll
        for (int it = 0; it < 4; ++it) {
            const int idx = it * 256 + t;          // chunk 0..1023
            const int row = idx >> 3;              // 0..127
            const int cg = (idx & 7) ^ (row & 7);  // swizzled chunk-of-8
            const __bf16* ga = Ab + row * M_ + koff + cg * 8;
            const __bf16* gb = Bb + row * M_ + koff + cg * 8;
            __builtin_amdgcn_global_load_lds(
                (const __attribute__((address_space(1))) void*)ga,
                (__attribute__((address_space(3))) void*)(&As[sb][(it * 256 + w * 64) * 8]),
                16, 0, 0);
            __builtin_amdgcn_global_load_lds(
                (const __attribute__((address_space(1))) void*)gb,
                (__attribute__((address_space(3))) void*)(&Bs[sb][(it * 256 + w * 64) * 8]),
                16, 0, 0);
        }
    };

    stage(0);
    for (int k0 = 0; k0 < 8; ++k0) {
        __syncthreads();                 // stage k0 data ready
        if (k0 + 1 < 8) stage(k0 + 1);   // prefetch flies during compute

        const int sb = k0 & 1;
        #pragma unroll
        for (int kk = 0; kk < 64; kk += 32) {
            bf16x8 af[4], bfr[4];
            #pragma unroll
            for (int mi = 0; mi < 4; ++mi) {
                const int row = wm * 64 + mi * 16 + l15;
                const int sc = ((kk >> 3) + quad) ^ (row & 7);
                af[mi] = *(const bf16x8*)(&As[sb][row * 64 + sc * 8]);
            }
            #pragma unroll
            for (int nj = 0; nj < 4; ++nj) {
                const int row = wn * 64 + nj * 16 + l15;
                const int sc = ((kk >> 3) + quad) ^ (row & 7);
                bfr[nj] = *(const bf16x8*)(&Bs[sb][row * 64 + sc * 8]);
            }
            #pragma unroll
            for (int mi = 0; mi < 4; ++mi)
                #pragma unroll
                for (int nj = 0; nj < 4; ++nj)
                    acc[mi][nj] = __builtin_amdgcn_mfma_f32_16x16x32_bf16(
                        af[mi], bfr[nj], acc[mi][nj], 0, 0, 0);
        }
    }

    // ---------------- epilogue ----------------
    const int gi0 = ti * 128 + wm * 64;
    const int gj0 = tj * 128 + wn * 64;
    const float* diagB = diag + b * D_;

    float di[4][4], dj[4];
    #pragma unroll
    for (int mi = 0; mi < 4; ++mi)
        #pragma unroll
        for (int r = 0; r < 4; ++r)
            di[mi][r] = diagB[gi0 + mi * 16 + quad * 4 + r];
    #pragma unroll
    for (int nj = 0; nj < 4; ++nj)
        dj[nj] = diagB[gj0 + nj * 16 + l15];

    float* outB = out + (size_t)b * OUTROW;
    float rs[4][4] = {};
    float cs[4] = {};
    float wt = 0.f;
    const float invK = 1.0f / 512.0f;  // dcov = di + dj - dot/512

    #pragma unroll
    for (int mi = 0; mi < 4; ++mi) {
        #pragma unroll
        for (int nj = 0; nj < 4; ++nj) {
            const f32x4 a = acc[mi][nj];
            const int j = gj0 + nj * 16 + l15;
            #pragma unroll
            for (int r = 0; r < 4; ++r) {
                const int i = gi0 + mi * 16 + quad * 4 + r;
                float d = di[mi][r] + dj[nj] - a[r] * invK;
                if (i == j) d = 0.0f;   // exact: ref has dcov(i,i) == 0
                d = fmaxf(d, 0.0f);
                const float p = __builtin_exp2f(ALPHA_ * __builtin_log2f(d + EPS_));
                rs[mi][r] += p;
                cs[nj] += p;
                wt += p;
                if (!diagTile || j >= i)
                    outB[(size_t)i * D_ - ((size_t)i * (i + 1)) / 2 + j] = p;
            }
        }
    }

    // row-sum contributions: reduce across l15 lanes
    #pragma unroll
    for (int mi = 0; mi < 4; ++mi) {
        #pragma unroll
        for (int r = 0; r < 4; ++r) {
            float v = rs[mi][r];
            v += __shfl_xor(v, 1); v += __shfl_xor(v, 2);
            v += __shfl_xor(v, 4); v += __shfl_xor(v, 8);
            if (l15 == 0)
                unsafeAtomicAdd(&rowsum[b * D_ + gi0 + mi * 16 + quad * 4 + r], v);
        }
    }
    // col-sum contributions map to rowsum[j] by symmetry (off-diag tiles only)
    if (!diagTile) {
        #pragma unroll
        for (int nj = 0; nj < 4; ++nj) {
            float v = cs[nj];
            v += __shfl_xor(v, 16); v += __shfl_xor(v, 32);
            if (quad == 0)
                unsafeAtomicAdd(&rowsum[b * D_ + gj0 + nj * 16 + l15], v);
        }
    }
    // batch total (off-diag tiles counted twice: tile + mirror)
    float v = wt;
    #pragma unroll
    for (int off = 32; off; off >>= 1) v += __shfl_down(v, off);
    if (l == 0) unsafeAtomicAdd(&totals[b], diagTile ? v : 2.0f * v);
}

// ---------------------------------------------------------------------------
// Kernel C: in-place double-centering. Block x=i handles rows i and 1023-i
// (pair length D+1 -> balanced). out[b,tri(i,j)] -= rm[i]+rm[j]-tm
// ---------------------------------------------------------------------------
__global__ __launch_bounds__(256) void center_kernel(
    float* __restrict__ out, const float* __restrict__ rowsum,
    const float* __restrict__ totals)
{
    const int b = blockIdx.y;
    const float* rsB = rowsum + b * D_;
    const float tm = totals[b] * (1.0f / ((float)D_ * (float)D_));
    float* outB = out + (size_t)b * OUTROW;

    #pragma unroll
    for (int half = 0; half < 2; ++half) {
        const int i = half ? (D_ - 1 - blockIdx.x) : blockIdx.x;
        const float rmi = rsB[i] * (1.0f / D_);
        float* row = outB + (size_t)i * D_ - ((size_t)i * (i + 1)) / 2;
        for (int j = i + threadIdx.x; j < D_; j += 256) {
            row[j] = row[j] - rmi - rsB[j] * (1.0f / D_) + tm;
        }
    }
}

// ---------------------------------------------------------------------------
extern "C" void kernel_launch(void* const* d_in, const int* in_sizes, int n_in,
                              void* d_out, int out_size, void* d_ws, size_t ws_size,
                              hipStream_t stream) {
    const float* feat = (const float*)d_in[0];
    float* out = (float*)d_out;

    char* ws = (char*)d_ws;
    __bf16* featbf = (__bf16*)ws;                            // 33,554,432 B
    float* diag    = (float*)(ws + 33554432);                //    131,072 B
    float* rowsum  = (float*)(ws + 33554432 + 131072);       //    131,072 B
    float* totals  = (float*)(ws + 33554432 + 262144);       //        128 B

    // zero rowsum + totals (ws is re-poisoned 0xAA before every launch)
    (void)hipMemsetAsync(rowsum, 0, 131072 + 128, stream);

    prep_kernel<<<dim3((B_ * D_) / 4), dim3(256), 0, stream>>>(feat, featbf, diag);
    gram_kernel<<<dim3(36 * B_), dim3(256), 0, stream>>>(featbf, diag, out, rowsum, totals);
    center_kernel<<<dim3(D_ / 2, B_), dim3(256), 0, stream>>>(out, rowsum, totals);
}